// Round 2
// baseline (597.613 us; speedup 1.0000x reference)
//
#include <hip/hip_runtime.h>
#include <cmath>

#define NLEV 16
#define HASH_PRIME 2654435761u

struct LvlC {
  float scale[NLEV];
  unsigned stride[NLEV];   // res + 1
  unsigned offset[NLEV];   // cumulative param offset (multiple of 8 -> even)
  unsigned hmask[NLEV];    // size-1 for hash levels (size==2^19), 0 for dense
};

__global__ __launch_bounds__(256) void hgp_kernel(
    const float* __restrict__ pts,
    const float2* __restrict__ txy,
    const float2* __restrict__ txz,
    const float2* __restrict__ tyz,
    float* __restrict__ out,
    LvlC lc, int n)
{
  int i = blockIdx.x * 256 + threadIdx.x;
  if (i >= n) return;

  // GridEncoder.forward input normalization: (x + 1) * 0.5
  float u0 = (pts[3 * i + 0] + 1.0f) * 0.5f;
  float u1 = (pts[3 * i + 1] + 1.0f) * 0.5f;
  float u2 = (pts[3 * i + 2] + 1.0f) * 0.5f;

  // COO_COMBS = (0,1), (0,2), (1,2)
  const float ua[3] = {u0, u0, u1};
  const float ub[3] = {u1, u2, u2};
  const float2* tabs[3] = {txy, txz, tyz};

  float* obase = out + (size_t)i * (2 * NLEV);

#pragma unroll
  for (int lp = 0; lp < NLEV / 2; ++lp) {
    float a0 = 0.f, a1 = 0.f, a2 = 0.f, a3 = 0.f;  // (lvl 2lp ch0/1, lvl 2lp+1 ch0/1)
#pragma unroll
    for (int h = 0; h < 2; ++h) {
      const int l = 2 * lp + h;
      const float sc = lc.scale[l];
      const unsigned o = lc.offset[l];
      const unsigned hm = lc.hmask[l];
      const unsigned s = lc.stride[l];
#pragma unroll
      for (int p = 0; p < 3; ++p) {
        const float2* t = tabs[p];
        float px = ua[p] * sc + 0.5f;
        float py = ub[p] * sc + 0.5f;
        float fx = floorf(px), fy = floorf(py);
        float rx = px - fx, ry = py - fy;
        unsigned x0 = (unsigned)fx, y0 = (unsigned)fy;
        float w00 = (1.f - rx) * (1.f - ry), w10 = rx * (1.f - ry);
        float w01 = (1.f - rx) * ry,         w11 = rx * ry;
        float v0, v1;
        if (hm) {
          // torch-ngp fast_hash: x ^ (y * prime), uint32 wrap; size is 2^19
          unsigned hy0 = y0 * HASH_PRIME;
          unsigned hy1 = hy0 + HASH_PRIME;  // (y0+1)*prime mod 2^32
          unsigned i00 = (x0 ^ hy0) & hm;
          unsigned i10 = ((x0 + 1u) ^ hy0) & hm;
          unsigned i01 = (x0 ^ hy1) & hm;
          unsigned i11 = ((x0 + 1u) ^ hy1) & hm;
          float2 f00 = t[o + i00];
          float2 f10 = t[o + i10];
          float2 f01 = t[o + i01];
          float2 f11 = t[o + i11];
          v0 = w00 * f00.x + w10 * f10.x + w01 * f01.x + w11 * f11.x;
          v1 = w00 * f00.y + w10 * f10.y + w01 * f01.y + w11 * f11.y;
        } else {
          // dense: corners (x0,y) and (x0+1,y) are adjacent entries ->
          // one 16B load per row (HW supports 8B-aligned float4 loads)
          unsigned i00 = x0 + y0 * s;
          float4 r0 = *reinterpret_cast<const float4*>(t + o + i00);      // f00,f10
          float4 r1 = *reinterpret_cast<const float4*>(t + o + i00 + s);  // f01,f11
          v0 = w00 * r0.x + w10 * r0.z + w01 * r1.x + w11 * r1.z;
          v1 = w00 * r0.y + w10 * r0.w + w01 * r1.y + w11 * r1.w;
        }
        if (h == 0) { a0 += v0; a1 += v1; } else { a2 += v0; a3 += v1; }
      }
    }
    *reinterpret_cast<float4*>(obase + 4 * lp) = make_float4(a0, a1, a2, a3);
  }
}

static void compute_levels(LvlC* lc)
{
  // Mirrors the Python _level_constants() with identical double-precision ops.
  const double pls = std::pow(2.0, std::log2(2048.0 / 16.0) / 15.0);
  unsigned long long off = 0;
  for (int l = 0; l < NLEV; ++l) {
    double s = 16.0 * std::pow(pls, (double)l) - 1.0;
    lc->scale[l] = (float)s;
    long long r = (long long)std::ceil(s) + 1;
    long long dense = (r + 1) * (r + 1);
    long long sz = dense < (1LL << 19) ? dense : (1LL << 19);
    sz = ((sz + 7) / 8) * 8;
    lc->stride[l] = (unsigned)(r + 1);
    lc->offset[l] = (unsigned)off;
    lc->hmask[l] = (dense > sz) ? (unsigned)(sz - 1) : 0u;  // hash size is 2^19 (pow2)
    off += (unsigned long long)sz;
  }
}

extern "C" void kernel_launch(void* const* d_in, const int* in_sizes, int n_in,
                              void* d_out, int out_size, void* d_ws, size_t ws_size,
                              hipStream_t stream) {
  const float*  pts = (const float*)d_in[0];
  const float2* txy = (const float2*)d_in[1];
  const float2* txz = (const float2*)d_in[2];
  const float2* tyz = (const float2*)d_in[3];
  float* out = (float*)d_out;

  int n = in_sizes[0] / 3;  // 1048576 points

  LvlC lc;
  compute_levels(&lc);

  int block = 256;
  int grid = (n + block - 1) / block;
  hgp_kernel<<<grid, block, 0, stream>>>(pts, txy, txz, tyz, out, lc, n);
}

// Round 3
// 505.218 us; speedup vs baseline: 1.1829x; 1.1829x over previous
//
#include <hip/hip_runtime.h>
#include <cmath>

#define NLEV 16
#define HASH_START 12               // levels >= 12 use spatial hash (verified: (776)^2 > 2^19 >= (563)^2)
#define HMASK ((1u << 19) - 1u)     // hash level size is exactly 2^19
#define HASH_PRIME 2654435761u

struct LvlC {
  float scale[NLEV];
  unsigned stride[NLEV];   // res + 1
  unsigned offset[NLEV];   // cumulative param offset (multiple of 8)
};

// 2 points per thread; level loop OUTERMOST so all resident waves sweep the
// (level, plane) tables in quasi-lockstep -> instantaneous working set ~4MB
// fits per-XCD L2 (vs 63MB interleaved = thrash to L3). Accumulate in VGPRs,
// one coalesced write at the end (avoids partial-line RMW write inflation).
__global__ __launch_bounds__(256) void hgp_kernel(
    const float* __restrict__ pts,
    const float2* __restrict__ txy,
    const float2* __restrict__ txz,
    const float2* __restrict__ tyz,
    float* __restrict__ out,
    LvlC lc, int half)
{
  int t = blockIdx.x * 256 + threadIdx.x;
  if (t >= half) return;
  const int idx0 = t, idx1 = t + half;

  // coords per point per plane: COO_COMBS = (0,1), (0,2), (1,2)
  float ua[2][3], ub[2][3];
  {
    float u0 = (pts[3 * idx0 + 0] + 1.0f) * 0.5f;
    float u1 = (pts[3 * idx0 + 1] + 1.0f) * 0.5f;
    float u2 = (pts[3 * idx0 + 2] + 1.0f) * 0.5f;
    ua[0][0] = u0; ub[0][0] = u1;
    ua[0][1] = u0; ub[0][1] = u2;
    ua[0][2] = u1; ub[0][2] = u2;
    float v0 = (pts[3 * idx1 + 0] + 1.0f) * 0.5f;
    float v1 = (pts[3 * idx1 + 1] + 1.0f) * 0.5f;
    float v2 = (pts[3 * idx1 + 2] + 1.0f) * 0.5f;
    ua[1][0] = v0; ub[1][0] = v1;
    ua[1][1] = v0; ub[1][1] = v2;
    ua[1][2] = v1; ub[1][2] = v2;
  }

  float acc[2][2 * NLEV];
#pragma unroll
  for (int k = 0; k < 2; ++k)
#pragma unroll
    for (int j = 0; j < 2 * NLEV; ++j) acc[k][j] = 0.0f;

  const float2* tabs[3] = {txy, txz, tyz};

#pragma unroll
  for (int l = 0; l < NLEV; ++l) {
    const float sc = lc.scale[l];
    const unsigned o = lc.offset[l];
    const unsigned s = lc.stride[l];
#pragma unroll
    for (int p = 0; p < 3; ++p) {
      const float2* tab = tabs[p];
      if (l >= HASH_START) {
        // hashed level: 4 independent 8B gathers per point, issue all 8 first
        float2 f[2][4];
        float w[2][4];
#pragma unroll
        for (int k = 0; k < 2; ++k) {
          float px = ua[k][p] * sc + 0.5f;
          float py = ub[k][p] * sc + 0.5f;
          float fx = floorf(px), fy = floorf(py);
          float rx = px - fx, ry = py - fy;
          unsigned x0 = (unsigned)fx, y0 = (unsigned)fy;
          unsigned hy0 = y0 * HASH_PRIME;
          unsigned hy1 = hy0 + HASH_PRIME;       // (y0+1)*prime mod 2^32
          f[k][0] = tab[o + ((x0 ^ hy0) & HMASK)];
          f[k][1] = tab[o + (((x0 + 1u) ^ hy0) & HMASK)];
          f[k][2] = tab[o + ((x0 ^ hy1) & HMASK)];
          f[k][3] = tab[o + (((x0 + 1u) ^ hy1) & HMASK)];
          w[k][0] = (1.f - rx) * (1.f - ry);
          w[k][1] = rx * (1.f - ry);
          w[k][2] = (1.f - rx) * ry;
          w[k][3] = rx * ry;
        }
#pragma unroll
        for (int k = 0; k < 2; ++k) {
          acc[k][2 * l + 0] += w[k][0] * f[k][0].x + w[k][1] * f[k][1].x +
                               w[k][2] * f[k][2].x + w[k][3] * f[k][3].x;
          acc[k][2 * l + 1] += w[k][0] * f[k][0].y + w[k][1] * f[k][1].y +
                               w[k][2] * f[k][2].y + w[k][3] * f[k][3].y;
        }
      } else {
        // dense level: two 16B row loads per point (corners adjacent)
        float4 r[2][2];
        float w[2][4];
#pragma unroll
        for (int k = 0; k < 2; ++k) {
          float px = ua[k][p] * sc + 0.5f;
          float py = ub[k][p] * sc + 0.5f;
          float fx = floorf(px), fy = floorf(py);
          float rx = px - fx, ry = py - fy;
          unsigned x0 = (unsigned)fx, y0 = (unsigned)fy;
          unsigned i00 = x0 + y0 * s;
          r[k][0] = *reinterpret_cast<const float4*>(tab + o + i00);      // f00,f10
          r[k][1] = *reinterpret_cast<const float4*>(tab + o + i00 + s);  // f01,f11
          w[k][0] = (1.f - rx) * (1.f - ry);
          w[k][1] = rx * (1.f - ry);
          w[k][2] = (1.f - rx) * ry;
          w[k][3] = rx * ry;
        }
#pragma unroll
        for (int k = 0; k < 2; ++k) {
          acc[k][2 * l + 0] += w[k][0] * r[k][0].x + w[k][1] * r[k][0].z +
                               w[k][2] * r[k][1].x + w[k][3] * r[k][1].z;
          acc[k][2 * l + 1] += w[k][0] * r[k][0].y + w[k][1] * r[k][0].w +
                               w[k][2] * r[k][1].y + w[k][3] * r[k][1].w;
        }
      }
    }
  }

  float4* o0 = (float4*)(out + (size_t)idx0 * (2 * NLEV));
  float4* o1 = (float4*)(out + (size_t)idx1 * (2 * NLEV));
#pragma unroll
  for (int j = 0; j < 8; ++j) {
    o0[j] = make_float4(acc[0][4 * j + 0], acc[0][4 * j + 1], acc[0][4 * j + 2], acc[0][4 * j + 3]);
    o1[j] = make_float4(acc[1][4 * j + 0], acc[1][4 * j + 1], acc[1][4 * j + 2], acc[1][4 * j + 3]);
  }
}

static void compute_levels(LvlC* lc)
{
  // Mirrors the Python _level_constants() with identical double-precision ops.
  const double pls = std::pow(2.0, std::log2(2048.0 / 16.0) / 15.0);
  unsigned long long off = 0;
  for (int l = 0; l < NLEV; ++l) {
    double s = 16.0 * std::pow(pls, (double)l) - 1.0;
    lc->scale[l] = (float)s;
    long long r = (long long)std::ceil(s) + 1;
    long long dense = (r + 1) * (r + 1);
    long long sz = dense < (1LL << 19) ? dense : (1LL << 19);
    sz = ((sz + 7) / 8) * 8;
    lc->stride[l] = (unsigned)(r + 1);
    lc->offset[l] = (unsigned)off;
    off += (unsigned long long)sz;
  }
}

extern "C" void kernel_launch(void* const* d_in, const int* in_sizes, int n_in,
                              void* d_out, int out_size, void* d_ws, size_t ws_size,
                              hipStream_t stream) {
  const float*  pts = (const float*)d_in[0];
  const float2* txy = (const float2*)d_in[1];
  const float2* txz = (const float2*)d_in[2];
  const float2* tyz = (const float2*)d_in[3];
  float* out = (float*)d_out;

  int n = in_sizes[0] / 3;  // 1048576 points
  int half = n / 2;

  LvlC lc;
  compute_levels(&lc);

  int block = 256;
  int grid = (half + block - 1) / block;
  hgp_kernel<<<grid, block, 0, stream>>>(pts, txy, txz, tyz, out, lc, half);
}